// Round 10
// baseline (164.337 us; speedup 1.0000x reference)
//
#include <hip/hip_runtime.h>
#include <hip/hip_fp16.h>
#include <math.h>

#define NPTS 131072
#define KCOMP 256
#define DIM 32
#define KF 608                    // 576 quad features (4-aligned rows) + 32 m
#define PSIF_BYTES 311296         // 19456 granules * 16 B (fp16 elements)
#define KC2_BYTES 1024
#define TAB_OFF (PSIF_BYTES + KC2_BYTES)
#define WS_NEED (TAB_OFF + 320)

typedef _Float16 f16x8 __attribute__((ext_vector_type(8)));
typedef __attribute__((ext_vector_type(16))) float f32x16;

__device__ __forceinline__ unsigned short f2h(float v) {
    __half h = __float2half(v);
    return __builtin_bit_cast(unsigned short, h);
}

// LDS-only barrier: drain lgkmcnt but leave global loads (vmcnt) in flight.
__device__ __forceinline__ void barrier_lds_only() {
    asm volatile("s_waitcnt lgkmcnt(0)\ns_barrier" ::: "memory");
}

__device__ __forceinline__ unsigned pkmul(unsigned a, unsigned b) {
    __half2 r = __builtin_bit_cast(__half2, a) * __builtin_bit_cast(__half2, b);
    return __builtin_bit_cast(unsigned, r);
}

// ---------------------------------------------------------------------------
// Precompute (verified r7-r9) + 80-entry gen table: site -> (d0,f00,d1,f01)
// ---------------------------------------------------------------------------
__global__ __launch_bounds__(256) void gmm_pre(
    const float* __restrict__ S,
    const float* __restrict__ centers,
    const float* __restrict__ weights,
    unsigned short* __restrict__ PsiF,
    float* __restrict__ kc2,
    unsigned* __restrict__ gTab)
{
    __shared__ float Sl[DIM][DIM + 1];
    __shared__ float As[DIM][DIM + 1];
    __shared__ float cl[DIM], ml[DIM];
    __shared__ float red[256];

    const int k = blockIdx.x, tid = threadIdx.x;

    if (k == 0 && tid < 80) {             // gen-site LUT (once)
        unsigned desc = 0;
        for (int qi = 0; qi < 2; ++qi) {
            const int p = (tid >> 3) * 64 + (tid & 7) * 8 + qi * 4;
            unsigned d, f;
            if (p >= 576) { d = 255u; f = (unsigned)(p - 576); }
            else {
                int dd = 0, pr = 0;
                while (true) {
                    const int len = ((32 - dd + 3) >> 2) << 2;
                    if (pr + len > p) break;
                    pr += len; ++dd;
                }
                d = (unsigned)dd;
                f = (unsigned)((dd & ~3) + (p - pr));
            }
            desc |= (d | (f << 8)) << (qi * 16);
        }
        gTab[tid] = desc;
    }

    for (int idx = tid; idx < DIM * DIM; idx += 256)
        Sl[idx >> 5][idx & 31] = S[(size_t)k * DIM * DIM + idx];
    if (tid < DIM) cl[tid] = centers[k * DIM + tid];
    __syncthreads();

    for (int idx = tid; idx < DIM * DIM; idx += 256) {
        const int d = idx >> 5, f = idx & 31;
        float a = 0.f;
#pragma unroll
        for (int e = 0; e < DIM; ++e) a = fmaf(Sl[d][e], Sl[f][e], a);
        As[d][f] = a;
    }
    __syncthreads();

    if (tid < DIM) {
        float mv = 0.f;
#pragma unroll
        for (int f = 0; f < DIM; ++f) mv = fmaf(As[tid][f], cl[f], mv);
        ml[tid] = mv;
    }
    __syncthreads();

    for (int p = tid; p < KF; p += 256) {
        float val;
        if (p < 576) {
            int d = 0, pr = 0;
            while (true) {
                const int len = ((32 - d + 3) >> 2) << 2;
                if (pr + len > p) break;
                pr += len; ++d;
            }
            const int f = (d & ~3) + (p - pr);
            val = (f < d) ? 0.f : ((f == d) ? -0.5f * As[d][d] : -As[d][f]);
        } else {
            val = ml[p - 576];
        }
        const int c = p >> 6, kk = p & 63;
        const int s = kk >> 4, qq = (kk >> 3) & 1, j = kk & 7;
        const int ct = k >> 5, ll = qq * 32 + (k & 31);
        const int g = c * 2048 + (s * 8 + ct) * 64 + ll;
        PsiF[(size_t)g * 8 + j] = f2h(val);
    }

    red[tid] = fabsf(weights[tid]);
    __syncthreads();
    for (int off = 128; off > 0; off >>= 1) {
        if (tid < off) red[tid] += red[tid + off];
        __syncthreads();
    }
    const float wsum = red[0];

    for (int j = 0; j < DIM - 1; ++j) {
        const float inv = 1.0f / As[j][j];
        for (int idx = tid; idx < DIM * DIM; idx += 256) {
            const int r = idx >> 5, c = idx & 31;
            if (r > j && c > j)
                As[r][c] = fmaf(-As[r][j] * inv, As[j][c], As[r][c]);
        }
        __syncthreads();
    }

    if (tid < DIM) red[tid] = __logf(As[tid][tid]);
    __syncthreads();
    if (tid == 0) {
        float sl = 0.f;
        for (int j = 0; j < DIM; ++j) sl += red[j];
        float cac = 0.f;
        for (int d2 = 0; d2 < DIM; ++d2) cac = fmaf(ml[d2], cl[d2], cac);
        kc2[k] = __logf(fabsf(weights[k])) - __logf(wsum + 1e-30f)
               + 0.5f * sl - 0.5f * cac;
    }
}

// ---------------------------------------------------------------------------
// Main: ROLLED K-loop (tiny hot body for I-cache). r9 tiling: 64 rows x 256
// cols, 4 waves of 64x64, LDS-A dbuf (1 lgkm barrier/chunk), register-B
// double-buffered one chunk ahead. Gen is table-driven (x fp16 in LDS).
// ---------------------------------------------------------------------------
__device__ __forceinline__ void quadR(const unsigned short* sx, int rowb,
                                      unsigned d, unsigned f0,
                                      unsigned& o0, unsigned& o1) {
    const bool mk = (d == 255u);
    const unsigned short* rp =
        (const unsigned short*)((const char*)sx + rowb);
    const unsigned xdu = rp[d & 31u];                       // clamped; mk discards
    const uint2 xf = *(const uint2*)((const char*)sx + rowb + f0 * 2u);
    const unsigned sd = __builtin_amdgcn_perm(xdu, xdu, 0x01000100u); // lo16 dup
    o0 = mk ? xf.x : pkmul(sd, xf.x);
    o1 = mk ? xf.y : pkmul(sd, xf.y);
}

__device__ __forceinline__ void genSiteR(const unsigned short* sx, int rowb,
                                         unsigned desc, uint4* buf,
                                         int row, int SS) {
    uint4 u;
    quadR(sx, rowb, desc & 255u, (desc >> 8) & 255u, u.x, u.y);
    quadR(sx, rowb, (desc >> 16) & 255u, desc >> 24, u.z, u.w);
    buf[(SS >> 1) * 128 + (row >> 5) * 64 + (SS & 1) * 32 + (row & 31)] = u;
}

__device__ __forceinline__ void genChunk(const unsigned short* sx, int rowb,
                                         const unsigned* sTab, int c, int cq,
                                         uint4* buf, int row, bool full) {
    genSiteR(sx, rowb, sTab[c * 8 + cq], buf, row, cq);
    if (full) genSiteR(sx, rowb, sTab[c * 8 + cq + 4], buf, row, cq + 4);
}

__device__ __forceinline__ void issueB(uint4 (&bf)[8], const uint4* pc) {
#pragma unroll
    for (int s = 0; s < 4; ++s)
#pragma unroll
        for (int ct = 0; ct < 2; ++ct)
            bf[s * 2 + ct] = pc[s * 512 + ct * 64];
}

template<int S>
__device__ __forceinline__ void stepR(const uint4* buf, const uint4 (&bf)[8],
                                      f32x16 (&acc)[2][2], int l) {
    const f16x8 a0 = __builtin_bit_cast(f16x8, buf[S * 128 + l]);
    const f16x8 a1 = __builtin_bit_cast(f16x8, buf[S * 128 + 64 + l]);
#pragma unroll
    for (int ct = 0; ct < 2; ++ct) {
        const f16x8 b = __builtin_bit_cast(f16x8, bf[S * 2 + ct]);
        acc[0][ct] = __builtin_amdgcn_mfma_f32_32x32x16_f16(a0, b, acc[0][ct], 0, 0, 0);
        acc[1][ct] = __builtin_amdgcn_mfma_f32_32x32x16_f16(a1, b, acc[1][ct], 0, 0, 0);
    }
}

__device__ __forceinline__ void mfma4(const uint4* buf, const uint4 (&bf)[8],
                                      f32x16 (&acc)[2][2], int l) {
    stepR<0>(buf, bf, acc, l); stepR<1>(buf, bf, acc, l);
    stepR<2>(buf, bf, acc, l); stepR<3>(buf, bf, acc, l);
}

__global__ __launch_bounds__(256, 2) void gmm_mfma(
    const float* __restrict__ points,
    const unsigned short* __restrict__ PsiF,
    const float* __restrict__ kc2,
    const unsigned* __restrict__ gTab,
    const float* __restrict__ thr,
    float* __restrict__ out)
{
    __shared__ unsigned short sxp[64 * 36];  // fp16 x, 72 B row stride
    __shared__ uint4 sA4[1024];              // A dbuf: [0:512) even, [512:1024) odd
    __shared__ unsigned sTab[80];
    __shared__ float sPm[64][4], sPs[64][4];

    const int t = threadIdx.x;
    const int cq = t >> 6, l = t & 63;
    const int row = l;
    const int rowb = row * 72;

    // stage x -> LDS fp16: thread (rr = t&63, q = t>>6) packs 8 elements
    {
        const int rr = t & 63, q = t >> 6;
        const float4* px = (const float4*)(points +
            ((size_t)blockIdx.x * 64 + rr) * DIM + q * 8);
        const float4 v0 = px[0], v1 = px[1];
        uint2 w0, w1;
        w0.x = __builtin_bit_cast(unsigned, __floats2half2_rn(v0.x, v0.y));
        w0.y = __builtin_bit_cast(unsigned, __floats2half2_rn(v0.z, v0.w));
        w1.x = __builtin_bit_cast(unsigned, __floats2half2_rn(v1.x, v1.y));
        w1.y = __builtin_bit_cast(unsigned, __floats2half2_rn(v1.z, v1.w));
        *(uint2*)((char*)sxp + rr * 72 + q * 16) = w0;
        *(uint2*)((char*)sxp + rr * 72 + q * 16 + 8) = w1;
    }
    if (t < 80) sTab[t] = gTab[t];
    __syncthreads();

    const uint4* pb = (const uint4*)PsiF + cq * 128 + l;

    uint4 bfA[8], bfB[8];
    issueB(bfA, pb);                         // chunk 0 in flight

    f32x16 acc[2][2];
#pragma unroll
    for (int a = 0; a < 2; ++a)
#pragma unroll
        for (int c = 0; c < 2; ++c)
#pragma unroll
            for (int r = 0; r < 16; ++r) acc[a][c][r] = 0.f;

    const uint4* pn = pb + 2048;             // next chunk's B

#pragma unroll 1
    for (int i = 0; i < 4; ++i) {            // chunks 2i, 2i+1  (0..7)
        genChunk(sxp, rowb, sTab, 2 * i, cq, sA4, row, true);
        issueB(bfB, pn); pn += 2048;         // chunk 2i+1
        barrier_lds_only();
        mfma4(sA4, bfA, acc, l);
        genChunk(sxp, rowb, sTab, 2 * i + 1, cq, sA4 + 512, row, true);
        issueB(bfA, pn); pn += 2048;         // chunk 2i+2 (<= 8)
        barrier_lds_only();
        mfma4(sA4 + 512, bfB, acc, l);
    }
    // chunk 8 (bfA holds it), prefetch chunk 9 -> bfB (over-read stays in ws)
    genChunk(sxp, rowb, sTab, 8, cq, sA4, row, true);
    issueB(bfB, pn);
    barrier_lds_only();
    mfma4(sA4, bfA, acc, l);
    // chunk 9: 2 valid K16-steps (m-features)
    genChunk(sxp, rowb, sTab, 9, cq, sA4 + 512, row, false);
    barrier_lds_only();
    stepR<0>(sA4 + 512, bfB, acc, l);
    stepR<1>(sA4 + 512, bfB, acc, l);

    // epilogue (r9-verified): per-wave LSE over 64 cols, combine via LDS
    float kcv[2];
#pragma unroll
    for (int ct = 0; ct < 2; ++ct) kcv[ct] = kc2[(cq * 2 + ct) * 32 + (l & 31)];

#pragma unroll
    for (int rt = 0; rt < 2; ++rt) {
#pragma unroll
        for (int rg = 0; rg < 16; ++rg) {
            const float v0 = acc[rt][0][rg] + kcv[0];
            const float v1 = acc[rt][1][rg] + kcv[1];
            float m = fmaxf(v0, v1);
#pragma unroll
            for (int mask = 1; mask < 32; mask <<= 1)
                m = fmaxf(m, __shfl_xor(m, mask, 64));
            float sv = __expf(v0 - m) + __expf(v1 - m);
#pragma unroll
            for (int mask = 1; mask < 32; mask <<= 1)
                sv += __shfl_xor(sv, mask, 64);
            if ((l & 31) == 0) {
                const int R = rt * 32 + (rg & 3) + 8 * (rg >> 2) + 4 * (l >> 5);
                sPm[R][cq] = m; sPs[R][cq] = sv;
            }
        }
    }
    __syncthreads();

    if (t < 64) {
        const float m0 = sPm[t][0], m1 = sPm[t][1];
        const float m2 = sPm[t][2], m3 = sPm[t][3];
        const float M = fmaxf(fmaxf(m0, m1), fmaxf(m2, m3));
        const float Sv = sPs[t][0] * __expf(m0 - M) + sPs[t][1] * __expf(m1 - M)
                       + sPs[t][2] * __expf(m2 - M) + sPs[t][3] * __expf(m3 - M);
        out[(size_t)blockIdx.x * 64 + t] = M + __logf(Sv) - thr[0];
    }
}

extern "C" void kernel_launch(void* const* d_in, const int* in_sizes, int n_in,
                              void* d_out, int out_size, void* d_ws, size_t ws_size,
                              hipStream_t stream) {
    const float* points  = (const float*)d_in[0];
    const float* centers = (const float*)d_in[1];
    const float* covs    = (const float*)d_in[2];
    const float* weights = (const float*)d_in[3];
    const float* thr     = (const float*)d_in[4];
    float* out = (float*)d_out;

    unsigned short* PsiF = (unsigned short*)d_ws;
    float* kc2 = (float*)((char*)d_ws + PSIF_BYTES);
    unsigned* gTab = (unsigned*)((char*)d_ws + TAB_OFF);

    gmm_pre<<<KCOMP, 256, 0, stream>>>(covs, centers, weights, PsiF, kc2, gTab);
    gmm_mfma<<<NPTS / 64, 256, 0, stream>>>(points, PsiF, kc2, gTab, thr, out);
}